// Round 12
// baseline (355.114 us; speedup 1.0000x reference)
//
#include <hip/hip_runtime.h>
#include <math.h>

// Problem constants (reference: N=8192, DIM=512, TOPK=10, all fp32)
#define NROWS 8192
#define DIMK  512
#define TOPK  10
#define SCALE 0.044194173824159223f   // fp32(512**-0.5)

// Phase-1 embed GEMM tiling (fp32 VALU): 128x64 tile (r32: was 128x128 —
// grid 512 = 2 blocks/CU capped occupancy at 19%), 8x4 micro, dbuf, ETK16
#define ETM 128
#define ETN 64
#define ETK 16
#define NTHREADS 256

// Screen GEMM tiling (bf16 MFMA): BN 256, 3-buf ring, phase-split + counted vmcnt
#define BM 128
#define BN 256
#define BK 32
#define NT (DIMK / BK)            // 16 K-tiles
#define ASZ (BM * BK)             // 4096 ushorts / buffer
#define BSZ (BN * BK)             // 8192 ushorts / buffer
#define SNT 512                   // screen threads: 8 waves, wave tile 64x64
#define NS2 16                    // column strips (grid 64x16 = 1024 blocks)
#define SCOLS2 (NROWS / NS2)      // 512 cols per strip (2 tiles of 256)
#define NQ 256                    // 32-col groups per row (8192/32)
#define CAP 64                    // max candidates per row
#define TMARGIN 2.0f              // bf16-gemm noise (~0.65) + bf16-storage (~0.35) << 2.0

typedef __attribute__((ext_vector_type(8))) short bf16x8;   // 8 bf16 = 4 VGPRs
typedef __attribute__((ext_vector_type(4))) float f32x4;
typedef __attribute__((ext_vector_type(2))) float f32x2;

__device__ __forceinline__ unsigned short f2bf(float f) {   // RNE fp32->bf16
  unsigned int u = __float_as_uint(f);
  u = (u + 0x7FFF + ((u >> 16) & 1)) >> 16;
  return (unsigned short)u;
}

// async global->LDS, 16B per lane; lds ptr must be wave-uniform base
__device__ __forceinline__ void gld16(const void* g, const void* lds) {
  __builtin_amdgcn_global_load_lds(
      (const __attribute__((address_space(1))) void*)g,
      (__attribute__((address_space(3))) void*)lds, 16, 0, 0);
}

// packed fp32 FMA: two INDEPENDENT exact IEEE fmas (v_pk_fma_f32). Each
// accumulator element's k-chain is unchanged -> bit-identical results.
__device__ __forceinline__ f32x2 pk_fma(f32x2 a, f32x2 b, f32x2 c) {
#if __has_builtin(__builtin_elementwise_fma)
  return __builtin_elementwise_fma(a, b, c);
#else
  f32x2 r; r[0] = fmaf(a[0], b[0], c[0]); r[1] = fmaf(a[1], b[1], c[1]);
  return r;
#endif
}

// ---------------------------------------------------------------------------
// Phase 1 (r32): ETN 128->64. r31 counters: grid 512 = 2 blocks/CU capped
// occupancy at 19% (r27's launch-bounds change was null because GRID was
// the cap); VALUBusy 56% == the per-wave VALU/LDS serialization ratio
// 64cyc/(64+48)cyc. Grid 64x16 = 1024 blocks = 4 blocks/CU = 16 waves/CU
// (2x TLP); LDS 25.6 KB. Per-element k-chain (ascending fmaf over k=0..511
// into one accumulator, bias at end) UNCHANGED -> Eh/Et BIT-IDENTICAL.
// ---------------------------------------------------------------------------
__global__ __launch_bounds__(NTHREADS, 4)
void embed_gemm(const float* __restrict__ X,
                const float* __restrict__ Wh, const float* __restrict__ bh,
                const float* __restrict__ Wt, const float* __restrict__ bt,
                float* __restrict__ Eh, float* __restrict__ Et,
                unsigned short* __restrict__ Ehb, unsigned short* __restrict__ Etb) {
  __shared__ float As[2][ETK][ETM + 4];   // 2 x 8.4 KB, d-major
  __shared__ float Bs[2][ETK][ETN + 4];   // 2 x 4.3 KB

  const int tid = threadIdx.x;
  const int rowBase = blockIdx.x * ETM;
  const int colBase = blockIdx.y * ETN;          // 0..960 over [Wh|Wt]
  const float* W  = (colBase < DIMK) ? Wh : Wt;
  const float* bb = (colBase < DIMK) ? bh : bt;
  float* Out            = (colBase < DIMK) ? Eh : Et;
  unsigned short* Outb  = (colBase < DIMK) ? Ehb : Etb;
  const int colOff = colBase & (DIMK - 1);

  const int tx = tid & 15, ty = tid >> 4;
  f32x2 acc2[8][2];
#pragma unroll
  for (int r = 0; r < 8; ++r)
#pragma unroll
    for (int p = 0; p < 2; ++p) acc2[r][p] = (f32x2){0.f, 0.f};

  auto stage = [&](int buf, int kt) {
#pragma unroll
    for (int u = 0; u < 2; ++u) {      // A tile: 512 float4 (4 per 16-k row)
      const int idx = tid + u * NTHREADS;
      const int r = idx >> 2;          // 0..127
      const int dc = idx & 3;          // k-quad within 16
      const float4 av = *(const float4*)&X[(size_t)(rowBase + r) * DIMK + kt + dc * 4];
      As[buf][dc * 4 + 0][r] = av.x; As[buf][dc * 4 + 1][r] = av.y;
      As[buf][dc * 4 + 2][r] = av.z; As[buf][dc * 4 + 3][r] = av.w;
    }
    {                                  // B tile: 256 float4 (1 per thread)
      const int r = tid >> 2;          // 0..63
      const int dc = tid & 3;
      const float4 bv = *(const float4*)&W[(size_t)(colOff + r) * DIMK + kt + dc * 4];
      Bs[buf][dc * 4 + 0][r] = bv.x; Bs[buf][dc * 4 + 1][r] = bv.y;
      Bs[buf][dc * 4 + 2][r] = bv.z; Bs[buf][dc * 4 + 3][r] = bv.w;
    }
  };
  auto compute = [&](int buf) {
#pragma unroll 4
    for (int k = 0; k < ETK; ++k) {
      const float4 a0 = *(const float4*)&As[buf][k][ty * 4];
      const float4 a1 = *(const float4*)&As[buf][k][64 + ty * 4];
      const float4 b0 = *(const float4*)&Bs[buf][k][tx * 4];
      const float ar[8] = {a0.x, a0.y, a0.z, a0.w, a1.x, a1.y, a1.z, a1.w};
      const f32x2 bp[2] = {(f32x2){b0.x, b0.y}, (f32x2){b0.z, b0.w}};
#pragma unroll
      for (int r = 0; r < 8; ++r) {
        const f32x2 ar2 = (f32x2){ar[r], ar[r]};
#pragma unroll
        for (int p = 0; p < 2; ++p)
          acc2[r][p] = pk_fma(ar2, bp[p], acc2[r][p]);
      }
    }
  };

  stage(0, 0);
  __syncthreads();
#pragma unroll 1
  for (int ki = 0; ki < DIMK / ETK; ki += 2) {
    if (ki + 1 < DIMK / ETK) stage(1, (ki + 1) * ETK);
    compute(0);                  // k ascending -> chain bit-identical
    __syncthreads();
    if (ki + 2 < DIMK / ETK) stage(0, (ki + 2) * ETK);
    compute(1);
    __syncthreads();
  }

  float br[4];
  {
    const float4 bv0 = *(const float4*)&bb[colOff + tx * 4];
    br[0] = bv0.x; br[1] = bv0.y; br[2] = bv0.z; br[3] = bv0.w;
  }
#pragma unroll
  for (int r = 0; r < 8; ++r) {
    const int row = rowBase + ((r < 4) ? (ty * 4 + r) : (64 + ty * 4 + r - 4));
    float4 o0;
    o0.x = acc2[r][0][0] + br[0]; o0.y = acc2[r][0][1] + br[1];
    o0.z = acc2[r][1][0] + br[2]; o0.w = acc2[r][1][1] + br[3];
    const size_t off0 = (size_t)row * DIMK + colOff + tx * 4;
    *(float4*)&Out[off0] = o0;
    ushort4 q0;
    q0.x = f2bf(o0.x); q0.y = f2bf(o0.y); q0.z = f2bf(o0.z); q0.w = f2bf(o0.w);
    *(ushort4*)&Outb[off0] = q0;
  }
}

// ---------------------------------------------------------------------------
// Screen (r31, kept byte-identical): phase-split + counted vmcnt + swizzle.
// First measured screen win (-15 us; confirmed the regime gate: the same
// counted-vmcnt that regressed as a coarse graft in r24 pays inside the
// phase-split). acc/Sc/tmax bit-identical to r26.
// ---------------------------------------------------------------------------
__global__ __launch_bounds__(SNT, 4)
void screen_store(const unsigned short* __restrict__ Ehb,
                  const unsigned short* __restrict__ Etb,
                  float* __restrict__ tmax, unsigned short* __restrict__ Sc) {
  __shared__ __align__(16) unsigned short pool[3 * (ASZ + BSZ)];   // 73728 B
  unsigned short* const Abase = pool;                 // 3 x 4096 ushorts
  unsigned short* const Bbase = pool + 3 * ASZ;       // 3 x 8192 ushorts
  unsigned short* const Csb = pool;   // epilogue alias: 128 x 72 = 18.4 KB

  const int tid = threadIdx.x;
  const int rowBase = blockIdx.x * BM;
  const int strip = blockIdx.y;

  const int w = tid >> 6, lane = tid & 63;
  const int q = lane >> 4, l15 = lane & 15;
  const int wr = (w & 1) * 64, wc = (w >> 1) * 64;   // 2x4 wave grid, 64x64 tiles
  const int rr = tid >> 2, sub = tid & 3;            // epilogue: row / 16B chunk pair

  const int wb0 = __builtin_amdgcn_readfirstlane(tid & ~63);
  const int ar0 = tid >> 2;
  // swizzled source chunk: chunk ^ ((row>>1)&3); row = tid>>2 so the
  // XOR key is (tid>>3)&3 (identical for the B slot tid+512: +128 rows
  // shifts (row>>1) by 64 = 0 mod 4). 4-lane groups read a permutation
  // of the same 64B line -> coalescing unchanged.
  const int acS = (((tid & 3) ^ ((tid >> 3) & 3))) * 8;

  // precomputed swizzled ds_read addrs (ushort units), fixed per thread
  int aAddr[4], bAddr[4];
#pragma unroll
  for (int i = 0; i < 4; ++i) {
    const int row = wr + i * 16 + l15;
    aAddr[i] = (row * 4 + (q ^ ((row >> 1) & 3))) * 8;
  }
#pragma unroll
  for (int j = 0; j < 4; ++j) {
    const int col = wc + j * 16 + l15;
    bAddr[j] = (col * 4 + (q ^ ((col >> 1) & 3))) * 8;
  }

  for (int ct = 0; ct < SCOLS2; ct += BN) {
    const int colBase = strip * SCOLS2 + ct;
    f32x4 acc[4][4];
#pragma unroll
    for (int i = 0; i < 4; ++i)
#pragma unroll
      for (int j = 0; j < 4; ++j) acc[i][j] = (f32x4){0.f, 0.f, 0.f, 0.f};

    auto stageS = [&](int bsel, int kt) {
      unsigned short* Ad = Abase + bsel * ASZ;
      unsigned short* Bd = Bbase + bsel * BSZ;
      gld16(Ehb + (size_t)(rowBase + ar0) * DIMK + kt + acS, Ad + wb0 * 8);
      gld16(Etb + (size_t)(colBase + ar0) * DIMK + kt + acS, Bd + wb0 * 8);
      gld16(Etb + (size_t)(colBase + 128 + ar0) * DIMK + kt + acS,
            Bd + (wb0 + 512) * 8);
    };

    // ring prologue: tiles 0,1 staged (6 outstanding); wait for tile 0
    stageS(0, 0);
    stageS(1, BK);
    asm volatile("s_waitcnt vmcnt(3)" ::: "memory");
    __builtin_amdgcn_s_barrier();
    asm volatile("" ::: "memory");

    int oc = 0, on = 1, op = 2;
#pragma unroll 1
    for (int t = 0; t < NT; ++t) {
      const unsigned short* Ac = Abase + oc * ASZ;
      const unsigned short* Bc = Bbase + oc * BSZ;
      bf16x8 af[4], bfr[4];
      // ---- phase 1: af[0..3] + bf[0..1], issue t+2 stage, MFMA j=0,1 ----
#pragma unroll
      for (int i = 0; i < 4; ++i) af[i] = *(const bf16x8*)&Ac[aAddr[i]];
#pragma unroll
      for (int j = 0; j < 2; ++j) bfr[j] = *(const bf16x8*)&Bc[bAddr[j]];
      if (t + 2 < NT) stageS(op, (t + 2) * BK);
      __builtin_amdgcn_s_setprio(1);
#pragma unroll
      for (int i = 0; i < 4; ++i)
#pragma unroll
        for (int j = 0; j < 2; ++j)
          acc[i][j] = __builtin_amdgcn_mfma_f32_16x16x32_bf16(af[i], bfr[j], acc[i][j], 0, 0, 0);
      __builtin_amdgcn_s_setprio(0);
      __builtin_amdgcn_s_barrier();      // mid-tile role-split barrier
      asm volatile("" ::: "memory");
      // ---- phase 2: bf[2..3], MFMA j=2,3 ----
#pragma unroll
      for (int j = 2; j < 4; ++j) bfr[j] = *(const bf16x8*)&Bc[bAddr[j]];
      __builtin_amdgcn_s_setprio(1);
#pragma unroll
      for (int i = 0; i < 4; ++i)
#pragma unroll
        for (int j = 2; j < 4; ++j)
          acc[i][j] = __builtin_amdgcn_mfma_f32_16x16x32_bf16(af[i], bfr[j], acc[i][j], 0, 0, 0);
      __builtin_amdgcn_s_setprio(0);
      if (t + 1 < NT) {
        // tile t+1's loads (issued at t-1) must be complete; t+2's 3 may fly
        if (t + 2 < NT) asm volatile("s_waitcnt vmcnt(3)" ::: "memory");
        else            asm volatile("s_waitcnt vmcnt(0)" ::: "memory");
        __builtin_amdgcn_s_barrier();
        asm volatile("" ::: "memory");
      }
      const int tmp = oc; oc = on; on = op; op = tmp;
    }
    __syncthreads();   // full drain: staging pool dead -> Csb alias valid.

#pragma unroll
    for (int qtr = 0; qtr < 4; ++qtr) {
      // dump: the 2 waves (row halves) owning this 64-col quarter
      if ((w >> 1) == qtr) {
#pragma unroll
        for (int i = 0; i < 4; ++i)
#pragma unroll
          for (int j = 0; j < 4; ++j)
#pragma unroll
            for (int rg = 0; rg < 4; ++rg)
              Csb[(wr + i * 16 + q * 4 + rg) * 72 + j * 16 + l15] =
                  f2bf(acc[i][j][rg]);
      }
      __syncthreads();
      // readback: 4 threads/row, 16 cols (2 uint4) each
      float m = -INFINITY;
      uint4 buf4[2];
#pragma unroll
      for (int k = 0; k < 2; ++k) {
        buf4[k] = *(const uint4*)&Csb[rr * 72 + sub * 16 + k * 8];
        const unsigned int uu[4] = {buf4[k].x, buf4[k].y, buf4[k].z, buf4[k].w};
#pragma unroll
        for (int e = 0; e < 4; ++e) {
          m = fmaxf(m, __uint_as_float(uu[e] << 16));
          m = fmaxf(m, __uint_as_float(uu[e] & 0xFFFF0000u));
        }
      }
      m = fmaxf(m, __shfl_xor(m, 1, 64));   // pair subs {0,1} / {2,3}: 32-col max
      const int gbase = (colBase + qtr * 64) >> 5;   // global 32-col group
      if ((sub & 1) == 0)
        tmax[(size_t)(rowBase + rr) * NQ + gbase + (sub >> 1)] = m;
      uint4* dst = (uint4*)&Sc[(size_t)(rowBase + rr) * NROWS + colBase + qtr * 64 + sub * 16];
      dst[0] = buf4[0];
      dst[1] = buf4[1];
      __syncthreads();   // readback done before next dump / next ct staging
    }
  }
}

// ---------------------------------------------------------------------------
// Merged tail (r8 exact, best measured): block-per-row chunk-skip collect +
// wave-0 rescore. r9/r10 restructures were null -> collect is bound by
// structure-invariant diverged-gather traffic; serial ascending-fmaf chain
// is load-bearing (r27). Keep verbatim.
// ---------------------------------------------------------------------------
__global__ __launch_bounds__(256)
void collect_rescore(const unsigned short* __restrict__ Sc,
                     const float* __restrict__ tmax,
                     const float* __restrict__ Eh, const float* __restrict__ Et,
                     float* __restrict__ out) {
  __shared__ float tm[NQ];     // 1 KB: the row's 256 group maxes
  __shared__ float tts;
  __shared__ int lcnt;
  __shared__ int lcand[CAP];
  const int tid = threadIdx.x;
  const int lane = tid & 63;
  const int wid = tid >> 6;
  const int r = blockIdx.x;

  if (tid == 0) lcnt = 0;
  tm[tid] = tmax[(size_t)r * NQ + tid];   // coalesced 1 KB row load
  __syncthreads();

  // --- threshold (wave 0): identical knockout semantics ---
  if (wid == 0) {
    float a0 = tm[lane * 4 + 0], a1 = tm[lane * 4 + 1];
    float a2 = tm[lane * 4 + 2], a3 = tm[lane * 4 + 3];
    float g = -INFINITY;
#pragma unroll 1
    for (int j = 0; j < TOPK; ++j) {
      const float lm = fmaxf(fmaxf(a0, a1), fmaxf(a2, a3));
      g = lm;
#pragma unroll
      for (int off = 32; off > 0; off >>= 1) g = fmaxf(g, __shfl_xor(g, off, 64));
      const unsigned long long ball = __ballot(lm == g);
      const int src = __ffsll((long long)ball) - 1;
      if (lane == src) {
        if      (a0 == g) a0 = -INFINITY;
        else if (a1 == g) a1 = -INFINITY;
        else if (a2 == g) a2 = -INFINITY;
        else              a3 = -INFINITY;
      }
    }
    if (lane == 0) tts = g - TMARGIN;
  }
  __syncthreads();
  const float tt = tts;

  // --- chunk-skip scan: thread t handles 32-col group t ---
  if (tm[tid] >= tt) {
    const unsigned short* chunk = Sc + (size_t)r * NROWS + tid * 32;
#pragma unroll
    for (int k = 0; k < 4; ++k) {
      const uint4 u = *(const uint4*)&chunk[k * 8];
      const unsigned int uu[4] = {u.x, u.y, u.z, u.w};
#pragma unroll
      for (int e = 0; e < 4; ++e) {
        const float lo = __uint_as_float(uu[e] << 16);
        const float hi = __uint_as_float(uu[e] & 0xFFFF0000u);
        const int c0 = tid * 32 + k * 8 + 2 * e;
        if (lo >= tt) {
          const int p = atomicAdd(&lcnt, 1);
          if (p < CAP) lcand[p] = c0;
        }
        if (hi >= tt) {
          const int p = atomicAdd(&lcnt, 1);
          if (p < CAP) lcand[p] = c0 + 1;
        }
      }
    }
  }
  __syncthreads();   // candidate list complete
  if (wid != 0) return;

  // --- rescore on wave 0: chain BIT-IDENTICAL (serial ascending fmaf) ---
  const int n = min(lcnt, CAP);
  const bool active = lane < n;
  const int col = active ? lcand[lane] : 0;

  const float* a = Eh + (size_t)r * DIMK;
  const float* b = Et + (size_t)col * DIMK;
  float p = 0.f;
#pragma unroll 4
  for (int k = 0; k < DIMK; k += 4) {
    const float4 av = *(const float4*)&a[k];
    const float4 bv = *(const float4*)&b[k];
    p = fmaf(av.x, bv.x, p);
    p = fmaf(av.y, bv.y, p);
    p = fmaf(av.z, bv.z, p);
    p = fmaf(av.w, bv.w, p);
  }
  float v = active ? p * SCALE : -INFINITY;
  const int vc = active ? col : 0x7FFFFFFF;

  // 10 rounds of wave-max (tie -> min col); lane j keeps round-j winner.
  float myv = -INFINITY; int myc = 0; float m = 0.f;
  float vv = v; int cc2 = vc;
#pragma unroll 1
  for (int j = 0; j < TOPK; ++j) {
    float bvv = vv; int bcc = cc2;
#pragma unroll
    for (int off = 32; off > 0; off >>= 1) {
      const float ov = __shfl_xor(bvv, off, 64);
      const int oc = __shfl_xor(bcc, off, 64);
      if (ov > bvv || (ov == bvv && oc < bcc)) { bvv = ov; bcc = oc; }
    }
    if (j == 0) m = bvv;
    if (lane == j) { myv = bvv; myc = bcc; }
    if (vv == bvv && cc2 == bcc) vv = -INFINITY;   // knock out (cols unique)
  }

  // softmax: gather the 10 values, sum sequentially (rank order, as before).
  float sum = 0.f;
#pragma unroll
  for (int j = 0; j < TOPK; ++j) sum += expf(__shfl(myv, j, 64) - m);
  const float inv = 1.0f / sum;

  if (lane < TOPK) {
    const size_t ro = (size_t)r * TOPK + lane;
    out[ro] = (float)r;                                   // src
    out[(size_t)NROWS * TOPK + ro] = (float)myc;          // dst
    out[2 * (size_t)NROWS * TOPK + ro] = expf(myv - m) * inv;  // weight
  }
}

// ---------------------------------------------------------------------------
extern "C" void kernel_launch(void* const* d_in, const int* in_sizes, int n_in,
                              void* d_out, int out_size, void* d_ws, size_t ws_size,
                              hipStream_t stream) {
  const float* X  = (const float*)d_in[0];
  const float* Wh = (const float*)d_in[1];
  const float* bh = (const float*)d_in[2];
  const float* Wt = (const float*)d_in[3];
  const float* bt = (const float*)d_in[4];
  float* out = (float*)d_out;

  char* ws = (char*)d_ws;
  const size_t embB  = (size_t)NROWS * DIMK * sizeof(float);          // 16 MB
  const size_t embBH = (size_t)NROWS * DIMK * sizeof(unsigned short); //  8 MB
  const size_t tmaxB = (size_t)NROWS * NQ * sizeof(float);            //  8 MB
  float* Eh   = (float*)ws;
  float* Et   = (float*)(ws + embB);
  unsigned short* Ehb = (unsigned short*)(ws + 2 * embB);
  unsigned short* Etb = (unsigned short*)(ws + 2 * embB + embBH);
  float* tmax = (float*)(ws + 2 * embB + 2 * embBH);
  unsigned short* Sc = (unsigned short*)(ws + 2 * embB + 2 * embBH + tmaxB);
  // total ws use ~176 MB

  dim3 blk(NTHREADS);
  dim3 g1(NROWS / ETM, (2 * DIMK) / ETN);      // 64 x 16 (1024 blocks)
  embed_gemm<<<g1, blk, 0, stream>>>(X, Wh, bh, Wt, bt, Eh, Et, Ehb, Etb);

  dim3 blkS(SNT);
  dim3 g2(NROWS / BM, NS2);                    // 64 x 16 (1024 blocks)
  screen_store<<<g2, blkS, 0, stream>>>(Ehb, Etb, tmax, Sc);

  collect_rescore<<<NROWS, blk, 0, stream>>>(Sc, tmax, Eh, Et, out);
}

// Round 13
// 346.748 us; speedup vs baseline: 1.0241x; 1.0241x over previous
//
#include <hip/hip_runtime.h>
#include <math.h>

// Problem constants (reference: N=8192, DIM=512, TOPK=10, all fp32)
#define NROWS 8192
#define DIMK  512
#define TOPK  10
#define SCALE 0.044194173824159223f   // fp32(512**-0.5)

// Phase-1 embed GEMM tiling (fp32 VALU): 128x128 tile, 8x8 micro, dbuf, ETK16
// (r13: ETN reverted 64->128 — r12's 8x4 micro added fragment-read instrs
// per output with no BW gain: A/B fragment reads are 16-lane broadcasts)
#define ETM 128
#define ETN 128
#define ETK 16
#define NTHREADS 256

// Screen GEMM tiling (bf16 MFMA): BN 256, 3-buf ring, phase-split + counted vmcnt
#define BM 128
#define BN 256
#define BK 32
#define NT (DIMK / BK)            // 16 K-tiles
#define ASZ (BM * BK)             // 4096 ushorts / buffer
#define BSZ (BN * BK)             // 8192 ushorts / buffer
#define SNT 512                   // screen threads: 8 waves, wave tile 64x64
#define NS2 16                    // column strips (grid 64x16 = 1024 blocks)
#define SCOLS2 (NROWS / NS2)      // 512 cols per strip (2 tiles of 256)
#define NQ 256                    // 32-col groups per row (8192/32)
#define CAP 64                    // max candidates per row
#define TMARGIN 2.0f              // bf16-gemm noise (~0.65) + bf16-storage (~0.35) << 2.0

typedef __attribute__((ext_vector_type(8))) short bf16x8;   // 8 bf16 = 4 VGPRs
typedef __attribute__((ext_vector_type(4))) float f32x4;
typedef __attribute__((ext_vector_type(2))) float f32x2;

__device__ __forceinline__ unsigned short f2bf(float f) {   // RNE fp32->bf16
  unsigned int u = __float_as_uint(f);
  u = (u + 0x7FFF + ((u >> 16) & 1)) >> 16;
  return (unsigned short)u;
}

// async global->LDS, 16B per lane; lds ptr must be wave-uniform base
__device__ __forceinline__ void gld16(const void* g, const void* lds) {
  __builtin_amdgcn_global_load_lds(
      (const __attribute__((address_space(1))) void*)g,
      (__attribute__((address_space(3))) void*)lds, 16, 0, 0);
}

// packed fp32 FMA: two INDEPENDENT exact IEEE fmas (v_pk_fma_f32). Each
// accumulator element's k-chain is unchanged -> bit-identical results.
__device__ __forceinline__ f32x2 pk_fma(f32x2 a, f32x2 b, f32x2 c) {
#if __has_builtin(__builtin_elementwise_fma)
  return __builtin_elementwise_fma(a, b, c);
#else
  f32x2 r; r[0] = fmaf(a[0], b[0], c[0]); r[1] = fmaf(a[1], b[1], c[1]);
  return r;
#endif
}

// ---------------------------------------------------------------------------
// Phase 1 (r11 exact, best measured 120 us): E = X @ W^T + b + bf16 copies.
// Occupancy levers exhausted (launch-bounds null r8, ETN=64 negative r12);
// VALUBusy ~56% at 2 blocks/CU = addr/unpack overhead + dep stalls. Parked.
// ---------------------------------------------------------------------------
__global__ __launch_bounds__(NTHREADS, 4)
void embed_gemm(const float* __restrict__ X,
                const float* __restrict__ Wh, const float* __restrict__ bh,
                const float* __restrict__ Wt, const float* __restrict__ bt,
                float* __restrict__ Eh, float* __restrict__ Et,
                unsigned short* __restrict__ Ehb, unsigned short* __restrict__ Etb) {
  __shared__ float As[2][ETK][ETM + 4];   // 2 x 8.4 KB, d-major
  __shared__ float Bs[2][ETK][ETN + 4];   // 2 x 8.4 KB

  const int tid = threadIdx.x;
  const int rowBase = blockIdx.x * ETM;
  const int colBase = blockIdx.y * ETN;          // 0..896 over [Wh|Wt]
  const float* W  = (colBase < DIMK) ? Wh : Wt;
  const float* bb = (colBase < DIMK) ? bh : bt;
  float* Out            = (colBase < DIMK) ? Eh : Et;
  unsigned short* Outb  = (colBase < DIMK) ? Ehb : Etb;
  const int colOff = colBase & (DIMK - 1);

  const int tx = tid & 15, ty = tid >> 4;
  f32x2 acc2[8][4];
#pragma unroll
  for (int r = 0; r < 8; ++r)
#pragma unroll
    for (int p = 0; p < 4; ++p) acc2[r][p] = (f32x2){0.f, 0.f};

  auto stage = [&](int buf, int kt) {
#pragma unroll
    for (int u = 0; u < 2; ++u) {      // A tile: 512 float4 (4 per 16-k row)
      const int idx = tid + u * NTHREADS;
      const int r = idx >> 2;          // 0..127
      const int dc = idx & 3;          // k-quad within 16
      const float4 av = *(const float4*)&X[(size_t)(rowBase + r) * DIMK + kt + dc * 4];
      As[buf][dc * 4 + 0][r] = av.x; As[buf][dc * 4 + 1][r] = av.y;
      As[buf][dc * 4 + 2][r] = av.z; As[buf][dc * 4 + 3][r] = av.w;
    }
#pragma unroll
    for (int u = 0; u < 2; ++u) {      // B tile: 512 float4
      const int idx = tid + u * NTHREADS;
      const int r = idx >> 2;
      const int dc = idx & 3;
      const float4 bv = *(const float4*)&W[(size_t)(colOff + r) * DIMK + kt + dc * 4];
      Bs[buf][dc * 4 + 0][r] = bv.x; Bs[buf][dc * 4 + 1][r] = bv.y;
      Bs[buf][dc * 4 + 2][r] = bv.z; Bs[buf][dc * 4 + 3][r] = bv.w;
    }
  };
  auto compute = [&](int buf) {
#pragma unroll 4
    for (int k = 0; k < ETK; ++k) {
      const float4 a0 = *(const float4*)&As[buf][k][ty * 4];
      const float4 a1 = *(const float4*)&As[buf][k][64 + ty * 4];
      const float4 b0 = *(const float4*)&Bs[buf][k][tx * 4];
      const float4 b1 = *(const float4*)&Bs[buf][k][64 + tx * 4];
      const float ar[8] = {a0.x, a0.y, a0.z, a0.w, a1.x, a1.y, a1.z, a1.w};
      const f32x2 bp[4] = {(f32x2){b0.x, b0.y}, (f32x2){b0.z, b0.w},
                           (f32x2){b1.x, b1.y}, (f32x2){b1.z, b1.w}};
#pragma unroll
      for (int r = 0; r < 8; ++r) {
        const f32x2 ar2 = (f32x2){ar[r], ar[r]};
#pragma unroll
        for (int p = 0; p < 4; ++p)
          acc2[r][p] = pk_fma(ar2, bp[p], acc2[r][p]);
      }
    }
  };

  stage(0, 0);
  __syncthreads();
#pragma unroll 1
  for (int ki = 0; ki < DIMK / ETK; ki += 2) {
    if (ki + 1 < DIMK / ETK) stage(1, (ki + 1) * ETK);
    compute(0);                  // k ascending -> chain bit-identical
    __syncthreads();
    if (ki + 2 < DIMK / ETK) stage(0, (ki + 2) * ETK);
    compute(1);
    __syncthreads();
  }

  float br[8];
  {
    const float4 bv0 = *(const float4*)&bb[colOff + tx * 4];
    const float4 bv1 = *(const float4*)&bb[colOff + 64 + tx * 4];
    br[0] = bv0.x; br[1] = bv0.y; br[2] = bv0.z; br[3] = bv0.w;
    br[4] = bv1.x; br[5] = bv1.y; br[6] = bv1.z; br[7] = bv1.w;
  }
#pragma unroll
  for (int r = 0; r < 8; ++r) {
    const int row = rowBase + ((r < 4) ? (ty * 4 + r) : (64 + ty * 4 + r - 4));
    float4 o0, o1;
    o0.x = acc2[r][0][0] + br[0]; o0.y = acc2[r][0][1] + br[1];
    o0.z = acc2[r][1][0] + br[2]; o0.w = acc2[r][1][1] + br[3];
    o1.x = acc2[r][2][0] + br[4]; o1.y = acc2[r][2][1] + br[5];
    o1.z = acc2[r][3][0] + br[6]; o1.w = acc2[r][3][1] + br[7];
    const size_t off0 = (size_t)row * DIMK + colOff + tx * 4;
    const size_t off1 = off0 + 64;
    *(float4*)&Out[off0] = o0;
    *(float4*)&Out[off1] = o1;
    ushort4 q0, q1;
    q0.x = f2bf(o0.x); q0.y = f2bf(o0.y); q0.z = f2bf(o0.z); q0.w = f2bf(o0.w);
    q1.x = f2bf(o1.x); q1.y = f2bf(o1.y); q1.z = f2bf(o1.z); q1.w = f2bf(o1.w);
    *(ushort4*)&Outb[off0] = q0;
    *(ushort4*)&Outb[off1] = q1;
  }
}

// ---------------------------------------------------------------------------
// Screen (r33 = r31 + 2-D XCD tile swizzle): r31's FETCH=72MB == Ehb 8MB +
// Etb 8MB x 8 XCDs (default linear%8 dispatch puts all 16 strips on every
// XCD; r23's regression empirically confirmed the %8 mapping). Bijective
// remap: XCD p's q-th resident group = one (8 rowTiles x 2 strips) tile ->
// 16 resident blocks share A 1MB + B 1MB << 4MB L2, BOTH reuse axes kept
// (r23's 1-D swizzle kept only B). Mapping-only -> output BIT-IDENTICAL.
// K-loop/phases byte-identical to r31 (first measured screen win).
// ---------------------------------------------------------------------------
__global__ __launch_bounds__(SNT, 4)
void screen_store(const unsigned short* __restrict__ Ehb,
                  const unsigned short* __restrict__ Etb,
                  float* __restrict__ tmax, unsigned short* __restrict__ Sc) {
  __shared__ __align__(16) unsigned short pool[3 * (ASZ + BSZ)];   // 73728 B
  unsigned short* const Abase = pool;                 // 3 x 4096 ushorts
  unsigned short* const Bbase = pool + 3 * ASZ;       // 3 x 8192 ushorts
  unsigned short* const Csb = pool;   // epilogue alias: 128 x 72 = 18.4 KB

  const int tid = threadIdx.x;
  // 2-D XCD tiling: orig -> (p=XCD, qq); tile_id = p + 8*(qq>>4) in [0,64);
  // wv = qq&15 indexes within the 8x2 tile. Bijective on 1024 blocks.
  const int orig = blockIdx.x + gridDim.x * blockIdx.y;
  const int p8 = orig & 7, qq = orig >> 3;
  const int tile_id = p8 + 8 * (qq >> 4);
  const int wv = qq & 15;
  const int rowBase = ((tile_id & 7) * 8 + (wv & 7)) * BM;
  const int strip = (tile_id >> 3) * 2 + (wv >> 3);

  const int w = tid >> 6, lane = tid & 63;
  const int q = lane >> 4, l15 = lane & 15;
  const int wr = (w & 1) * 64, wc = (w >> 1) * 64;   // 2x4 wave grid, 64x64 tiles
  const int rr = tid >> 2, sub = tid & 3;            // epilogue: row / 16B chunk pair

  const int wb0 = __builtin_amdgcn_readfirstlane(tid & ~63);
  const int ar0 = tid >> 2;
  // swizzled source chunk: chunk ^ ((row>>1)&3); row = tid>>2 so the
  // XOR key is (tid>>3)&3 (identical for the B slot tid+512). 4-lane
  // groups read a permutation of the same 64B line -> coalescing intact.
  const int acS = (((tid & 3) ^ ((tid >> 3) & 3))) * 8;

  // precomputed swizzled ds_read addrs (ushort units), fixed per thread
  int aAddr[4], bAddr[4];
#pragma unroll
  for (int i = 0; i < 4; ++i) {
    const int row = wr + i * 16 + l15;
    aAddr[i] = (row * 4 + (q ^ ((row >> 1) & 3))) * 8;
  }
#pragma unroll
  for (int j = 0; j < 4; ++j) {
    const int col = wc + j * 16 + l15;
    bAddr[j] = (col * 4 + (q ^ ((col >> 1) & 3))) * 8;
  }

  for (int ct = 0; ct < SCOLS2; ct += BN) {
    const int colBase = strip * SCOLS2 + ct;
    f32x4 acc[4][4];
#pragma unroll
    for (int i = 0; i < 4; ++i)
#pragma unroll
      for (int j = 0; j < 4; ++j) acc[i][j] = (f32x4){0.f, 0.f, 0.f, 0.f};

    auto stageS = [&](int bsel, int kt) {
      unsigned short* Ad = Abase + bsel * ASZ;
      unsigned short* Bd = Bbase + bsel * BSZ;
      gld16(Ehb + (size_t)(rowBase + ar0) * DIMK + kt + acS, Ad + wb0 * 8);
      gld16(Etb + (size_t)(colBase + ar0) * DIMK + kt + acS, Bd + wb0 * 8);
      gld16(Etb + (size_t)(colBase + 128 + ar0) * DIMK + kt + acS,
            Bd + (wb0 + 512) * 8);
    };

    // ring prologue: tiles 0,1 staged (6 outstanding); wait for tile 0
    stageS(0, 0);
    stageS(1, BK);
    asm volatile("s_waitcnt vmcnt(3)" ::: "memory");
    __builtin_amdgcn_s_barrier();
    asm volatile("" ::: "memory");

    int oc = 0, on = 1, op = 2;
#pragma unroll 1
    for (int t = 0; t < NT; ++t) {
      const unsigned short* Ac = Abase + oc * ASZ;
      const unsigned short* Bc = Bbase + oc * BSZ;
      bf16x8 af[4], bfr[4];
      // ---- phase 1: af[0..3] + bf[0..1], issue t+2 stage, MFMA j=0,1 ----
#pragma unroll
      for (int i = 0; i < 4; ++i) af[i] = *(const bf16x8*)&Ac[aAddr[i]];
#pragma unroll
      for (int j = 0; j < 2; ++j) bfr[j] = *(const bf16x8*)&Bc[bAddr[j]];
      if (t + 2 < NT) stageS(op, (t + 2) * BK);
      __builtin_amdgcn_s_setprio(1);
#pragma unroll
      for (int i = 0; i < 4; ++i)
#pragma unroll
        for (int j = 0; j < 2; ++j)
          acc[i][j] = __builtin_amdgcn_mfma_f32_16x16x32_bf16(af[i], bfr[j], acc[i][j], 0, 0, 0);
      __builtin_amdgcn_s_setprio(0);
      __builtin_amdgcn_s_barrier();      // mid-tile role-split barrier
      asm volatile("" ::: "memory");
      // ---- phase 2: bf[2..3], MFMA j=2,3 ----
#pragma unroll
      for (int j = 2; j < 4; ++j) bfr[j] = *(const bf16x8*)&Bc[bAddr[j]];
      __builtin_amdgcn_s_setprio(1);
#pragma unroll
      for (int i = 0; i < 4; ++i)
#pragma unroll
        for (int j = 2; j < 4; ++j)
          acc[i][j] = __builtin_amdgcn_mfma_f32_16x16x32_bf16(af[i], bfr[j], acc[i][j], 0, 0, 0);
      __builtin_amdgcn_s_setprio(0);
      if (t + 1 < NT) {
        // tile t+1's loads (issued at t-1) must be complete; t+2's 3 may fly
        if (t + 2 < NT) asm volatile("s_waitcnt vmcnt(3)" ::: "memory");
        else            asm volatile("s_waitcnt vmcnt(0)" ::: "memory");
        __builtin_amdgcn_s_barrier();
        asm volatile("" ::: "memory");
      }
      const int tmp = oc; oc = on; on = op; op = tmp;
    }
    __syncthreads();   // full drain: staging pool dead -> Csb alias valid.

#pragma unroll
    for (int qtr = 0; qtr < 4; ++qtr) {
      // dump: the 2 waves (row halves) owning this 64-col quarter
      if ((w >> 1) == qtr) {
#pragma unroll
        for (int i = 0; i < 4; ++i)
#pragma unroll
          for (int j = 0; j < 4; ++j)
#pragma unroll
            for (int rg = 0; rg < 4; ++rg)
              Csb[(wr + i * 16 + q * 4 + rg) * 72 + j * 16 + l15] =
                  f2bf(acc[i][j][rg]);
      }
      __syncthreads();
      // readback: 4 threads/row, 16 cols (2 uint4) each
      float m = -INFINITY;
      uint4 buf4[2];
#pragma unroll
      for (int k = 0; k < 2; ++k) {
        buf4[k] = *(const uint4*)&Csb[rr * 72 + sub * 16 + k * 8];
        const unsigned int uu[4] = {buf4[k].x, buf4[k].y, buf4[k].z, buf4[k].w};
#pragma unroll
        for (int e = 0; e < 4; ++e) {
          m = fmaxf(m, __uint_as_float(uu[e] << 16));
          m = fmaxf(m, __uint_as_float(uu[e] & 0xFFFF0000u));
        }
      }
      m = fmaxf(m, __shfl_xor(m, 1, 64));   // pair subs {0,1} / {2,3}: 32-col max
      const int gbase = (colBase + qtr * 64) >> 5;   // global 32-col group
      if ((sub & 1) == 0)
        tmax[(size_t)(rowBase + rr) * NQ + gbase + (sub >> 1)] = m;
      uint4* dst = (uint4*)&Sc[(size_t)(rowBase + rr) * NROWS + colBase + qtr * 64 + sub * 16];
      dst[0] = buf4[0];
      dst[1] = buf4[1];
      __syncthreads();   // readback done before next dump / next ct staging
    }
  }
}

// ---------------------------------------------------------------------------
// Merged tail (r8 exact, best measured): block-per-row chunk-skip collect +
// wave-0 rescore. r9/r10 restructures were null -> collect is bound by
// structure-invariant diverged-gather traffic; serial ascending-fmaf chain
// is load-bearing (r27). Keep verbatim.
// ---------------------------------------------------------------------------
__global__ __launch_bounds__(256)
void collect_rescore(const unsigned short* __restrict__ Sc,
                     const float* __restrict__ tmax,
                     const float* __restrict__ Eh, const float* __restrict__ Et,
                     float* __restrict__ out) {
  __shared__ float tm[NQ];     // 1 KB: the row's 256 group maxes
  __shared__ float tts;
  __shared__ int lcnt;
  __shared__ int lcand[CAP];
  const int tid = threadIdx.x;
  const int lane = tid & 63;
  const int wid = tid >> 6;
  const int r = blockIdx.x;

  if (tid == 0) lcnt = 0;
  tm[tid] = tmax[(size_t)r * NQ + tid];   // coalesced 1 KB row load
  __syncthreads();

  // --- threshold (wave 0): identical knockout semantics ---
  if (wid == 0) {
    float a0 = tm[lane * 4 + 0], a1 = tm[lane * 4 + 1];
    float a2 = tm[lane * 4 + 2], a3 = tm[lane * 4 + 3];
    float g = -INFINITY;
#pragma unroll 1
    for (int j = 0; j < TOPK; ++j) {
      const float lm = fmaxf(fmaxf(a0, a1), fmaxf(a2, a3));
      g = lm;
#pragma unroll
      for (int off = 32; off > 0; off >>= 1) g = fmaxf(g, __shfl_xor(g, off, 64));
      const unsigned long long ball = __ballot(lm == g);
      const int src = __ffsll((long long)ball) - 1;
      if (lane == src) {
        if      (a0 == g) a0 = -INFINITY;
        else if (a1 == g) a1 = -INFINITY;
        else if (a2 == g) a2 = -INFINITY;
        else              a3 = -INFINITY;
      }
    }
    if (lane == 0) tts = g - TMARGIN;
  }
  __syncthreads();
  const float tt = tts;

  // --- chunk-skip scan: thread t handles 32-col group t ---
  if (tm[tid] >= tt) {
    const unsigned short* chunk = Sc + (size_t)r * NROWS + tid * 32;
#pragma unroll
    for (int k = 0; k < 4; ++k) {
      const uint4 u = *(const uint4*)&chunk[k * 8];
      const unsigned int uu[4] = {u.x, u.y, u.z, u.w};
#pragma unroll
      for (int e = 0; e < 4; ++e) {
        const float lo = __uint_as_float(uu[e] << 16);
        const float hi = __uint_as_float(uu[e] & 0xFFFF0000u);
        const int c0 = tid * 32 + k * 8 + 2 * e;
        if (lo >= tt) {
          const int p = atomicAdd(&lcnt, 1);
          if (p < CAP) lcand[p] = c0;
        }
        if (hi >= tt) {
          const int p = atomicAdd(&lcnt, 1);
          if (p < CAP) lcand[p] = c0 + 1;
        }
      }
    }
  }
  __syncthreads();   // candidate list complete
  if (wid != 0) return;

  // --- rescore on wave 0: chain BIT-IDENTICAL (serial ascending fmaf) ---
  const int n = min(lcnt, CAP);
  const bool active = lane < n;
  const int col = active ? lcand[lane] : 0;

  const float* a = Eh + (size_t)r * DIMK;
  const float* b = Et + (size_t)col * DIMK;
  float p = 0.f;
#pragma unroll 4
  for (int k = 0; k < DIMK; k += 4) {
    const float4 av = *(const float4*)&a[k];
    const float4 bv = *(const float4*)&b[k];
    p = fmaf(av.x, bv.x, p);
    p = fmaf(av.y, bv.y, p);
    p = fmaf(av.z, bv.z, p);
    p = fmaf(av.w, bv.w, p);
  }
  float v = active ? p * SCALE : -INFINITY;
  const int vc = active ? col : 0x7FFFFFFF;

  // 10 rounds of wave-max (tie -> min col); lane j keeps round-j winner.
  float myv = -INFINITY; int myc = 0; float m = 0.f;
  float vv = v; int cc2 = vc;
#pragma unroll 1
  for (int j = 0; j < TOPK; ++j) {
    float bvv = vv; int bcc = cc2;
#pragma unroll
    for (int off = 32; off > 0; off >>= 1) {
      const float ov = __shfl_xor(bvv, off, 64);
      const int oc = __shfl_xor(bcc, off, 64);
      if (ov > bvv || (ov == bvv && oc < bcc)) { bvv = ov; bcc = oc; }
    }
    if (j == 0) m = bvv;
    if (lane == j) { myv = bvv; myc = bcc; }
    if (vv == bvv && cc2 == bcc) vv = -INFINITY;   // knock out (cols unique)
  }

  // softmax: gather the 10 values, sum sequentially (rank order, as before).
  float sum = 0.f;
#pragma unroll
  for (int j = 0; j < TOPK; ++j) sum += expf(__shfl(myv, j, 64) - m);
  const float inv = 1.0f / sum;

  if (lane < TOPK) {
    const size_t ro = (size_t)r * TOPK + lane;
    out[ro] = (float)r;                                   // src
    out[(size_t)NROWS * TOPK + ro] = (float)myc;          // dst
    out[2 * (size_t)NROWS * TOPK + ro] = expf(myv - m) * inv;  // weight
  }
}

// ---------------------------------------------------------------------------
extern "C" void kernel_launch(void* const* d_in, const int* in_sizes, int n_in,
                              void* d_out, int out_size, void* d_ws, size_t ws_size,
                              hipStream_t stream) {
  const float* X  = (const float*)d_in[0];
  const float* Wh = (const float*)d_in[1];
  const float* bh = (const float*)d_in[2];
  const float* Wt = (const float*)d_in[3];
  const float* bt = (const float*)d_in[4];
  float* out = (float*)d_out;

  char* ws = (char*)d_ws;
  const size_t embB  = (size_t)NROWS * DIMK * sizeof(float);          // 16 MB
  const size_t embBH = (size_t)NROWS * DIMK * sizeof(unsigned short); //  8 MB
  const size_t tmaxB = (size_t)NROWS * NQ * sizeof(float);            //  8 MB
  float* Eh   = (float*)ws;
  float* Et   = (float*)(ws + embB);
  unsigned short* Ehb = (unsigned short*)(ws + 2 * embB);
  unsigned short* Etb = (unsigned short*)(ws + 2 * embB + embBH);
  float* tmax = (float*)(ws + 2 * embB + 2 * embBH);
  unsigned short* Sc = (unsigned short*)(ws + 2 * embB + 2 * embBH + tmaxB);
  // total ws use ~176 MB

  dim3 blk(NTHREADS);
  dim3 g1(NROWS / ETM, (2 * DIMK) / ETN);      // 64 x 8
  embed_gemm<<<g1, blk, 0, stream>>>(X, Wh, bh, Wt, bt, Eh, Et, Ehb, Etb);

  dim3 blkS(SNT);
  dim3 g2(NROWS / BM, NS2);                    // 64 x 16 (1024 blocks)
  screen_store<<<g2, blkS, 0, stream>>>(Ehb, Etb, tmax, Sc);

  collect_rescore<<<NROWS, blk, 0, stream>>>(Sc, tmax, Eh, Et, out);
}

// Round 14
// 345.847 us; speedup vs baseline: 1.0268x; 1.0026x over previous
//
#include <hip/hip_runtime.h>
#include <math.h>

// Problem constants (reference: N=8192, DIM=512, TOPK=10, all fp32)
#define NROWS 8192
#define DIMK  512
#define TOPK  10
#define SCALE 0.044194173824159223f   // fp32(512**-0.5)

// Phase-1 embed GEMM tiling (fp32 VALU): 128x128 tile, 8x8 micro, ETK16,
// r34: T14 3-stage register pipeline (load t+1 regs | compute t | write LDS)
#define ETM 128
#define ETN 128
#define ETK 16
#define NTHREADS 256

// Screen GEMM tiling (bf16 MFMA): BN 256, 3-buf ring, phase-split + counted vmcnt
#define BM 128
#define BN 256
#define BK 32
#define NT (DIMK / BK)            // 16 K-tiles
#define ASZ (BM * BK)             // 4096 ushorts / buffer
#define BSZ (BN * BK)             // 8192 ushorts / buffer
#define SNT 512                   // screen threads: 8 waves, wave tile 64x64
#define NS2 16                    // column strips (grid 64x16 = 1024 blocks)
#define SCOLS2 (NROWS / NS2)      // 512 cols per strip (2 tiles of 256)
#define NQ 256                    // 32-col groups per row (8192/32)
#define CAP 64                    // max candidates per row
#define TMARGIN 2.0f              // bf16-gemm noise (~0.65) + bf16-storage (~0.35) << 2.0

typedef __attribute__((ext_vector_type(8))) short bf16x8;   // 8 bf16 = 4 VGPRs
typedef __attribute__((ext_vector_type(4))) float f32x4;
typedef __attribute__((ext_vector_type(2))) float f32x2;

__device__ __forceinline__ unsigned short f2bf(float f) {   // RNE fp32->bf16
  unsigned int u = __float_as_uint(f);
  u = (u + 0x7FFF + ((u >> 16) & 1)) >> 16;
  return (unsigned short)u;
}

// async global->LDS, 16B per lane; lds ptr must be wave-uniform base
__device__ __forceinline__ void gld16(const void* g, const void* lds) {
  __builtin_amdgcn_global_load_lds(
      (const __attribute__((address_space(1))) void*)g,
      (__attribute__((address_space(3))) void*)lds, 16, 0, 0);
}

// packed fp32 FMA: two INDEPENDENT exact IEEE fmas (v_pk_fma_f32). Each
// accumulator element's k-chain is unchanged -> bit-identical results.
__device__ __forceinline__ f32x2 pk_fma(f32x2 a, f32x2 b, f32x2 c) {
#if __has_builtin(__builtin_elementwise_fma)
  return __builtin_elementwise_fma(a, b, c);
#else
  f32x2 r; r[0] = fmaf(a[0], b[0], c[0]); r[1] = fmaf(a[1], b[1], c[1]);
  return r;
#endif
}

// ---------------------------------------------------------------------------
// Phase 1 (r34): same math/layout as r11 (BIT-IDENTICAL Eh/Et), staging
// restructured as T14 async split. r11-r13 counters: VALUBusy 55%, HBM 7%,
// occupancy-invariant (2x occ null twice) -> per-wave stall: each of 32
// stage phases did global-load + immediate LDS scatter-write, so the
// barrier behind the writes ate ~900cyc HBM latency 32x. Now: loads for
// tile t+1 issue BEFORE compute(t) (~1100 cyc cover); the dependent LDS
// writes run AFTER compute; one barrier/tile (same count). Same values,
// same write pattern, same compute order -> chain untouched. +16 VGPR.
// ---------------------------------------------------------------------------
__global__ __launch_bounds__(NTHREADS, 4)
void embed_gemm(const float* __restrict__ X,
                const float* __restrict__ Wh, const float* __restrict__ bh,
                const float* __restrict__ Wt, const float* __restrict__ bt,
                float* __restrict__ Eh, float* __restrict__ Et,
                unsigned short* __restrict__ Ehb, unsigned short* __restrict__ Etb) {
  __shared__ float As[2][ETK][ETM + 4];   // 2 x 8.4 KB, d-major
  __shared__ float Bs[2][ETK][ETN + 4];   // 2 x 8.4 KB

  const int tid = threadIdx.x;
  const int rowBase = blockIdx.x * ETM;
  const int colBase = blockIdx.y * ETN;          // 0..896 over [Wh|Wt]
  const float* W  = (colBase < DIMK) ? Wh : Wt;
  const float* bb = (colBase < DIMK) ? bh : bt;
  float* Out            = (colBase < DIMK) ? Eh : Et;
  unsigned short* Outb  = (colBase < DIMK) ? Ehb : Etb;
  const int colOff = colBase & (DIMK - 1);

  const int tx = tid & 15, ty = tid >> 4;
  // staging geometry: slot u covers idx = tid + u*256 -> row idx>>2, quad idx&3
  const int r0 = tid >> 2,           dc0 = tid & 3;
  const int r1 = (tid + 256) >> 2,   dc1 = (tid + 256) & 3;

  f32x2 acc2[8][4];
#pragma unroll
  for (int r = 0; r < 8; ++r)
#pragma unroll
    for (int p = 0; p < 4; ++p) acc2[r][p] = (f32x2){0.f, 0.f};

  float4 rA[2], rB[2];   // T14 register stage for the NEXT tile
  auto loadRegs = [&](int kt) {
    rA[0] = *(const float4*)&X[(size_t)(rowBase + r0) * DIMK + kt + dc0 * 4];
    rA[1] = *(const float4*)&X[(size_t)(rowBase + r1) * DIMK + kt + dc1 * 4];
    rB[0] = *(const float4*)&W[(size_t)(colOff + r0) * DIMK + kt + dc0 * 4];
    rB[1] = *(const float4*)&W[(size_t)(colOff + r1) * DIMK + kt + dc1 * 4];
  };
  auto writeLds = [&](int buf) {
    As[buf][dc0 * 4 + 0][r0] = rA[0].x; As[buf][dc0 * 4 + 1][r0] = rA[0].y;
    As[buf][dc0 * 4 + 2][r0] = rA[0].z; As[buf][dc0 * 4 + 3][r0] = rA[0].w;
    As[buf][dc1 * 4 + 0][r1] = rA[1].x; As[buf][dc1 * 4 + 1][r1] = rA[1].y;
    As[buf][dc1 * 4 + 2][r1] = rA[1].z; As[buf][dc1 * 4 + 3][r1] = rA[1].w;
    Bs[buf][dc0 * 4 + 0][r0] = rB[0].x; Bs[buf][dc0 * 4 + 1][r0] = rB[0].y;
    Bs[buf][dc0 * 4 + 2][r0] = rB[0].z; Bs[buf][dc0 * 4 + 3][r0] = rB[0].w;
    Bs[buf][dc1 * 4 + 0][r1] = rB[1].x; Bs[buf][dc1 * 4 + 1][r1] = rB[1].y;
    Bs[buf][dc1 * 4 + 2][r1] = rB[1].z; Bs[buf][dc1 * 4 + 3][r1] = rB[1].w;
  };
  auto compute = [&](int buf) {
#pragma unroll 4
    for (int k = 0; k < ETK; ++k) {
      const float4 a0 = *(const float4*)&As[buf][k][ty * 4];
      const float4 a1 = *(const float4*)&As[buf][k][64 + ty * 4];
      const float4 b0 = *(const float4*)&Bs[buf][k][tx * 4];
      const float4 b1 = *(const float4*)&Bs[buf][k][64 + tx * 4];
      const float ar[8] = {a0.x, a0.y, a0.z, a0.w, a1.x, a1.y, a1.z, a1.w};
      const f32x2 bp[4] = {(f32x2){b0.x, b0.y}, (f32x2){b0.z, b0.w},
                           (f32x2){b1.x, b1.y}, (f32x2){b1.z, b1.w}};
#pragma unroll
      for (int r = 0; r < 8; ++r) {
        const f32x2 ar2 = (f32x2){ar[r], ar[r]};
#pragma unroll
        for (int p = 0; p < 4; ++p)
          acc2[r][p] = pk_fma(ar2, bp[p], acc2[r][p]);
      }
    }
  };

  // prologue: tile 0 -> LDS, tile 1 -> regs
  loadRegs(0);
  writeLds(0);
  __syncthreads();
  loadRegs(ETK);

#pragma unroll 1
  for (int ki = 0; ki < DIMK / ETK; ++ki) {
    compute(ki & 1);                       // covers the in-flight regs loads
    if (ki + 1 < DIMK / ETK) writeLds((ki + 1) & 1);   // vmcnt lands HERE
    __syncthreads();                       // writes visible to all waves
    if (ki + 2 < DIMK / ETK) loadRegs((ki + 2) * ETK); // covered by next compute
  }

  float br[8];
  {
    const float4 bv0 = *(const float4*)&bb[colOff + tx * 4];
    const float4 bv1 = *(const float4*)&bb[colOff + 64 + tx * 4];
    br[0] = bv0.x; br[1] = bv0.y; br[2] = bv0.z; br[3] = bv0.w;
    br[4] = bv1.x; br[5] = bv1.y; br[6] = bv1.z; br[7] = bv1.w;
  }
#pragma unroll
  for (int r = 0; r < 8; ++r) {
    const int row = rowBase + ((r < 4) ? (ty * 4 + r) : (64 + ty * 4 + r - 4));
    float4 o0, o1;
    o0.x = acc2[r][0][0] + br[0]; o0.y = acc2[r][0][1] + br[1];
    o0.z = acc2[r][1][0] + br[2]; o0.w = acc2[r][1][1] + br[3];
    o1.x = acc2[r][2][0] + br[4]; o1.y = acc2[r][2][1] + br[5];
    o1.z = acc2[r][3][0] + br[6]; o1.w = acc2[r][3][1] + br[7];
    const size_t off0 = (size_t)row * DIMK + colOff + tx * 4;
    const size_t off1 = off0 + 64;
    *(float4*)&Out[off0] = o0;
    *(float4*)&Out[off1] = o1;
    ushort4 q0, q1;
    q0.x = f2bf(o0.x); q0.y = f2bf(o0.y); q0.z = f2bf(o0.z); q0.w = f2bf(o0.w);
    q1.x = f2bf(o1.x); q1.y = f2bf(o1.y); q1.z = f2bf(o1.z); q1.w = f2bf(o1.w);
    *(ushort4*)&Outb[off0] = q0;
    *(ushort4*)&Outb[off1] = q1;
  }
}

// ---------------------------------------------------------------------------
// Screen (r31 exact, part of the 340.6-us best build): phase-split +
// counted vmcnt + swizzle, default block order. r33's 2-D XCD remap was
// neutral-to-negative -> reverted. Screen closed out.
// ---------------------------------------------------------------------------
__global__ __launch_bounds__(SNT, 4)
void screen_store(const unsigned short* __restrict__ Ehb,
                  const unsigned short* __restrict__ Etb,
                  float* __restrict__ tmax, unsigned short* __restrict__ Sc) {
  __shared__ __align__(16) unsigned short pool[3 * (ASZ + BSZ)];   // 73728 B
  unsigned short* const Abase = pool;                 // 3 x 4096 ushorts
  unsigned short* const Bbase = pool + 3 * ASZ;       // 3 x 8192 ushorts
  unsigned short* const Csb = pool;   // epilogue alias: 128 x 72 = 18.4 KB

  const int tid = threadIdx.x;
  const int rowBase = blockIdx.x * BM;
  const int strip = blockIdx.y;

  const int w = tid >> 6, lane = tid & 63;
  const int q = lane >> 4, l15 = lane & 15;
  const int wr = (w & 1) * 64, wc = (w >> 1) * 64;   // 2x4 wave grid, 64x64 tiles
  const int rr = tid >> 2, sub = tid & 3;            // epilogue: row / 16B chunk pair

  const int wb0 = __builtin_amdgcn_readfirstlane(tid & ~63);
  const int ar0 = tid >> 2;
  // swizzled source chunk: chunk ^ ((row>>1)&3); row = tid>>2 so the
  // XOR key is (tid>>3)&3 (identical for the B slot tid+512). 4-lane
  // groups read a permutation of the same 64B line -> coalescing intact.
  const int acS = (((tid & 3) ^ ((tid >> 3) & 3))) * 8;

  // precomputed swizzled ds_read addrs (ushort units), fixed per thread
  int aAddr[4], bAddr[4];
#pragma unroll
  for (int i = 0; i < 4; ++i) {
    const int row = wr + i * 16 + l15;
    aAddr[i] = (row * 4 + (q ^ ((row >> 1) & 3))) * 8;
  }
#pragma unroll
  for (int j = 0; j < 4; ++j) {
    const int col = wc + j * 16 + l15;
    bAddr[j] = (col * 4 + (q ^ ((col >> 1) & 3))) * 8;
  }

  for (int ct = 0; ct < SCOLS2; ct += BN) {
    const int colBase = strip * SCOLS2 + ct;
    f32x4 acc[4][4];
#pragma unroll
    for (int i = 0; i < 4; ++i)
#pragma unroll
      for (int j = 0; j < 4; ++j) acc[i][j] = (f32x4){0.f, 0.f, 0.f, 0.f};

    auto stageS = [&](int bsel, int kt) {
      unsigned short* Ad = Abase + bsel * ASZ;
      unsigned short* Bd = Bbase + bsel * BSZ;
      gld16(Ehb + (size_t)(rowBase + ar0) * DIMK + kt + acS, Ad + wb0 * 8);
      gld16(Etb + (size_t)(colBase + ar0) * DIMK + kt + acS, Bd + wb0 * 8);
      gld16(Etb + (size_t)(colBase + 128 + ar0) * DIMK + kt + acS,
            Bd + (wb0 + 512) * 8);
    };

    // ring prologue: tiles 0,1 staged (6 outstanding); wait for tile 0
    stageS(0, 0);
    stageS(1, BK);
    asm volatile("s_waitcnt vmcnt(3)" ::: "memory");
    __builtin_amdgcn_s_barrier();
    asm volatile("" ::: "memory");

    int oc = 0, on = 1, op = 2;
#pragma unroll 1
    for (int t = 0; t < NT; ++t) {
      const unsigned short* Ac = Abase + oc * ASZ;
      const unsigned short* Bc = Bbase + oc * BSZ;
      bf16x8 af[4], bfr[4];
      // ---- phase 1: af[0..3] + bf[0..1], issue t+2 stage, MFMA j=0,1 ----
#pragma unroll
      for (int i = 0; i < 4; ++i) af[i] = *(const bf16x8*)&Ac[aAddr[i]];
#pragma unroll
      for (int j = 0; j < 2; ++j) bfr[j] = *(const bf16x8*)&Bc[bAddr[j]];
      if (t + 2 < NT) stageS(op, (t + 2) * BK);
      __builtin_amdgcn_s_setprio(1);
#pragma unroll
      for (int i = 0; i < 4; ++i)
#pragma unroll
        for (int j = 0; j < 2; ++j)
          acc[i][j] = __builtin_amdgcn_mfma_f32_16x16x32_bf16(af[i], bfr[j], acc[i][j], 0, 0, 0);
      __builtin_amdgcn_s_setprio(0);
      __builtin_amdgcn_s_barrier();      // mid-tile role-split barrier
      asm volatile("" ::: "memory");
      // ---- phase 2: bf[2..3], MFMA j=2,3 ----
#pragma unroll
      for (int j = 2; j < 4; ++j) bfr[j] = *(const bf16x8*)&Bc[bAddr[j]];
      __builtin_amdgcn_s_setprio(1);
#pragma unroll
      for (int i = 0; i < 4; ++i)
#pragma unroll
        for (int j = 2; j < 4; ++j)
          acc[i][j] = __builtin_amdgcn_mfma_f32_16x16x32_bf16(af[i], bfr[j], acc[i][j], 0, 0, 0);
      __builtin_amdgcn_s_setprio(0);
      if (t + 1 < NT) {
        // tile t+1's loads (issued at t-1) must be complete; t+2's 3 may fly
        if (t + 2 < NT) asm volatile("s_waitcnt vmcnt(3)" ::: "memory");
        else            asm volatile("s_waitcnt vmcnt(0)" ::: "memory");
        __builtin_amdgcn_s_barrier();
        asm volatile("" ::: "memory");
      }
      const int tmp = oc; oc = on; on = op; op = tmp;
    }
    __syncthreads();   // full drain: staging pool dead -> Csb alias valid.

#pragma unroll
    for (int qtr = 0; qtr < 4; ++qtr) {
      // dump: the 2 waves (row halves) owning this 64-col quarter
      if ((w >> 1) == qtr) {
#pragma unroll
        for (int i = 0; i < 4; ++i)
#pragma unroll
          for (int j = 0; j < 4; ++j)
#pragma unroll
            for (int rg = 0; rg < 4; ++rg)
              Csb[(wr + i * 16 + q * 4 + rg) * 72 + j * 16 + l15] =
                  f2bf(acc[i][j][rg]);
      }
      __syncthreads();
      // readback: 4 threads/row, 16 cols (2 uint4) each
      float m = -INFINITY;
      uint4 buf4[2];
#pragma unroll
      for (int k = 0; k < 2; ++k) {
        buf4[k] = *(const uint4*)&Csb[rr * 72 + sub * 16 + k * 8];
        const unsigned int uu[4] = {buf4[k].x, buf4[k].y, buf4[k].z, buf4[k].w};
#pragma unroll
        for (int e = 0; e < 4; ++e) {
          m = fmaxf(m, __uint_as_float(uu[e] << 16));
          m = fmaxf(m, __uint_as_float(uu[e] & 0xFFFF0000u));
        }
      }
      m = fmaxf(m, __shfl_xor(m, 1, 64));   // pair subs {0,1} / {2,3}: 32-col max
      const int gbase = (colBase + qtr * 64) >> 5;   // global 32-col group
      if ((sub & 1) == 0)
        tmax[(size_t)(rowBase + rr) * NQ + gbase + (sub >> 1)] = m;
      uint4* dst = (uint4*)&Sc[(size_t)(rowBase + rr) * NROWS + colBase + qtr * 64 + sub * 16];
      dst[0] = buf4[0];
      dst[1] = buf4[1];
      __syncthreads();   // readback done before next dump / next ct staging
    }
  }
}

// ---------------------------------------------------------------------------
// Merged tail (r8 exact, best measured): block-per-row chunk-skip collect +
// wave-0 rescore. r9/r10 restructures were null -> collect is bound by
// structure-invariant diverged-gather traffic; serial ascending-fmaf chain
// is load-bearing (r27). Keep verbatim.
// ---------------------------------------------------------------------------
__global__ __launch_bounds__(256)
void collect_rescore(const unsigned short* __restrict__ Sc,
                     const float* __restrict__ tmax,
                     const float* __restrict__ Eh, const float* __restrict__ Et,
                     float* __restrict__ out) {
  __shared__ float tm[NQ];     // 1 KB: the row's 256 group maxes
  __shared__ float tts;
  __shared__ int lcnt;
  __shared__ int lcand[CAP];
  const int tid = threadIdx.x;
  const int lane = tid & 63;
  const int wid = tid >> 6;
  const int r = blockIdx.x;

  if (tid == 0) lcnt = 0;
  tm[tid] = tmax[(size_t)r * NQ + tid];   // coalesced 1 KB row load
  __syncthreads();

  // --- threshold (wave 0): identical knockout semantics ---
  if (wid == 0) {
    float a0 = tm[lane * 4 + 0], a1 = tm[lane * 4 + 1];
    float a2 = tm[lane * 4 + 2], a3 = tm[lane * 4 + 3];
    float g = -INFINITY;
#pragma unroll 1
    for (int j = 0; j < TOPK; ++j) {
      const float lm = fmaxf(fmaxf(a0, a1), fmaxf(a2, a3));
      g = lm;
#pragma unroll
      for (int off = 32; off > 0; off >>= 1) g = fmaxf(g, __shfl_xor(g, off, 64));
      const unsigned long long ball = __ballot(lm == g);
      const int src = __ffsll((long long)ball) - 1;
      if (lane == src) {
        if      (a0 == g) a0 = -INFINITY;
        else if (a1 == g) a1 = -INFINITY;
        else if (a2 == g) a2 = -INFINITY;
        else              a3 = -INFINITY;
      }
    }
    if (lane == 0) tts = g - TMARGIN;
  }
  __syncthreads();
  const float tt = tts;

  // --- chunk-skip scan: thread t handles 32-col group t ---
  if (tm[tid] >= tt) {
    const unsigned short* chunk = Sc + (size_t)r * NROWS + tid * 32;
#pragma unroll
    for (int k = 0; k < 4; ++k) {
      const uint4 u = *(const uint4*)&chunk[k * 8];
      const unsigned int uu[4] = {u.x, u.y, u.z, u.w};
#pragma unroll
      for (int e = 0; e < 4; ++e) {
        const float lo = __uint_as_float(uu[e] << 16);
        const float hi = __uint_as_float(uu[e] & 0xFFFF0000u);
        const int c0 = tid * 32 + k * 8 + 2 * e;
        if (lo >= tt) {
          const int p = atomicAdd(&lcnt, 1);
          if (p < CAP) lcand[p] = c0;
        }
        if (hi >= tt) {
          const int p = atomicAdd(&lcnt, 1);
          if (p < CAP) lcand[p] = c0 + 1;
        }
      }
    }
  }
  __syncthreads();   // candidate list complete
  if (wid != 0) return;

  // --- rescore on wave 0: chain BIT-IDENTICAL (serial ascending fmaf) ---
  const int n = min(lcnt, CAP);
  const bool active = lane < n;
  const int col = active ? lcand[lane] : 0;

  const float* a = Eh + (size_t)r * DIMK;
  const float* b = Et + (size_t)col * DIMK;
  float p = 0.f;
#pragma unroll 4
  for (int k = 0; k < DIMK; k += 4) {
    const float4 av = *(const float4*)&a[k];
    const float4 bv = *(const float4*)&b[k];
    p = fmaf(av.x, bv.x, p);
    p = fmaf(av.y, bv.y, p);
    p = fmaf(av.z, bv.z, p);
    p = fmaf(av.w, bv.w, p);
  }
  float v = active ? p * SCALE : -INFINITY;
  const int vc = active ? col : 0x7FFFFFFF;

  // 10 rounds of wave-max (tie -> min col); lane j keeps round-j winner.
  float myv = -INFINITY; int myc = 0; float m = 0.f;
  float vv = v; int cc2 = vc;
#pragma unroll 1
  for (int j = 0; j < TOPK; ++j) {
    float bvv = vv; int bcc = cc2;
#pragma unroll
    for (int off = 32; off > 0; off >>= 1) {
      const float ov = __shfl_xor(bvv, off, 64);
      const int oc = __shfl_xor(bcc, off, 64);
      if (ov > bvv || (ov == bvv && oc < bcc)) { bvv = ov; bcc = oc; }
    }
    if (j == 0) m = bvv;
    if (lane == j) { myv = bvv; myc = bcc; }
    if (vv == bvv && cc2 == bcc) vv = -INFINITY;   // knock out (cols unique)
  }

  // softmax: gather the 10 values, sum sequentially (rank order, as before).
  float sum = 0.f;
#pragma unroll
  for (int j = 0; j < TOPK; ++j) sum += expf(__shfl(myv, j, 64) - m);
  const float inv = 1.0f / sum;

  if (lane < TOPK) {
    const size_t ro = (size_t)r * TOPK + lane;
    out[ro] = (float)r;                                   // src
    out[(size_t)NROWS * TOPK + ro] = (float)myc;          // dst
    out[2 * (size_t)NROWS * TOPK + ro] = expf(myv - m) * inv;  // weight
  }
}

// ---------------------------------------------------------------------------
extern "C" void kernel_launch(void* const* d_in, const int* in_sizes, int n_in,
                              void* d_out, int out_size, void* d_ws, size_t ws_size,
                              hipStream_t stream) {
  const float* X  = (const float*)d_in[0];
  const float* Wh = (const float*)d_in[1];
  const float* bh = (const float*)d_in[2];
  const float* Wt = (const float*)d_in[3];
  const float* bt = (const float*)d_in[4];
  float* out = (float*)d_out;

  char* ws = (char*)d_ws;
  const size_t embB  = (size_t)NROWS * DIMK * sizeof(float);          // 16 MB
  const size_t embBH = (size_t)NROWS * DIMK * sizeof(unsigned short); //  8 MB
  const size_t tmaxB = (size_t)NROWS * NQ * sizeof(float);            //  8 MB
  float* Eh   = (float*)ws;
  float* Et   = (float*)(ws + embB);
  unsigned short* Ehb = (unsigned short*)(ws + 2 * embB);
  unsigned short* Etb = (unsigned short*)(ws + 2 * embB + embBH);
  float* tmax = (float*)(ws + 2 * embB + 2 * embBH);
  unsigned short* Sc = (unsigned short*)(ws + 2 * embB + 2 * embBH + tmaxB);
  // total ws use ~176 MB

  dim3 blk(NTHREADS);
  dim3 g1(NROWS / ETM, (2 * DIMK) / ETN);      // 64 x 8
  embed_gemm<<<g1, blk, 0, stream>>>(X, Wh, bh, Wt, bt, Eh, Et, Ehb, Etb);

  dim3 blkS(SNT);
  dim3 g2(NROWS / BM, NS2);                    // 64 x 16 (1024 blocks)
  screen_store<<<g2, blkS, 0, stream>>>(Ehb, Etb, tmax, Sc);

  collect_rescore<<<NROWS, blk, 0, stream>>>(Sc, tmax, Eh, Et, out);
}

// Round 15
// 336.710 us; speedup vs baseline: 1.0547x; 1.0271x over previous
//
#include <hip/hip_runtime.h>
#include <math.h>

// Problem constants (reference: N=8192, DIM=512, TOPK=10, all fp32)
#define NROWS 8192
#define DIMK  512
#define TOPK  10
#define SCALE 0.044194173824159223f   // fp32(512**-0.5)

// Phase-1 embed GEMM tiling (fp32 VALU): 128x128 tile, 8x8 micro, dbuf, ETK16
#define ETM 128
#define ETN 128
#define ETK 16
#define NTHREADS 256

// Screen GEMM tiling (bf16 MFMA): BN 256, 3-buf ring, phase-split + counted vmcnt
#define BM 128
#define BN 256
#define BK 32
#define NT (DIMK / BK)            // 16 K-tiles
#define ASZ (BM * BK)             // 4096 ushorts / buffer
#define BSZ (BN * BK)             // 8192 ushorts / buffer
#define SNT 512                   // screen threads: 8 waves, wave tile 64x64
#define NS2 16                    // column strips (grid 64x16 = 1024 blocks)
#define SCOLS2 (NROWS / NS2)      // 512 cols per strip (2 tiles of 256)
#define NQ 256                    // 32-col groups per row (8192/32)
#define CAP 64                    // max candidates per row
#define TMARGIN 2.0f              // bf16-gemm noise (~0.65) + bf16-storage (~0.35) << 2.0

typedef __attribute__((ext_vector_type(8))) short bf16x8;   // 8 bf16 = 4 VGPRs
typedef __attribute__((ext_vector_type(4))) float f32x4;
typedef __attribute__((ext_vector_type(2))) float f32x2;

__device__ __forceinline__ unsigned short f2bf(float f) {   // RNE fp32->bf16
  unsigned int u = __float_as_uint(f);
  u = (u + 0x7FFF + ((u >> 16) & 1)) >> 16;
  return (unsigned short)u;
}

// async global->LDS, 16B per lane; lds ptr must be wave-uniform base
__device__ __forceinline__ void gld16(const void* g, const void* lds) {
  __builtin_amdgcn_global_load_lds(
      (const __attribute__((address_space(1))) void*)g,
      (__attribute__((address_space(3))) void*)lds, 16, 0, 0);
}

// packed fp32 FMA: two INDEPENDENT exact IEEE fmas (v_pk_fma_f32). Each
// accumulator element's k-chain is unchanged -> bit-identical results.
__device__ __forceinline__ f32x2 pk_fma(f32x2 a, f32x2 b, f32x2 c) {
#if __has_builtin(__builtin_elementwise_fma)
  return __builtin_elementwise_fma(a, b, c);
#else
  f32x2 r; r[0] = fmaf(a[0], b[0], c[0]); r[1] = fmaf(a[1], b[1], c[1]);
  return r;
#endif
}

// ---------------------------------------------------------------------------
// Phase 1 (r11 exact, the 340.6-us best build): E = X @ W^T + b + bf16
// copies. Embed is per-wave ISSUE-SERIALIZED: per k-step 32 pk_fma (64cyc)
// + 4 ds_read_b128 (48cyc) = 112cyc -> VALU fraction 57% == measured.
// All occupancy/pipeline levers null (r8 launch-bounds, r12 ETN=64 -7us,
// r14 T14 null: compiler already splits load/use). Structural floor for
// the bit-exact fp32 chain (MFMA forbidden: bf16 would flip top-k ranks).
// ---------------------------------------------------------------------------
__global__ __launch_bounds__(NTHREADS, 4)
void embed_gemm(const float* __restrict__ X,
                const float* __restrict__ Wh, const float* __restrict__ bh,
                const float* __restrict__ Wt, const float* __restrict__ bt,
                float* __restrict__ Eh, float* __restrict__ Et,
                unsigned short* __restrict__ Ehb, unsigned short* __restrict__ Etb) {
  __shared__ float As[2][ETK][ETM + 4];   // 2 x 8.4 KB, d-major
  __shared__ float Bs[2][ETK][ETN + 4];   // 2 x 8.4 KB

  const int tid = threadIdx.x;
  const int rowBase = blockIdx.x * ETM;
  const int colBase = blockIdx.y * ETN;          // 0..896 over [Wh|Wt]
  const float* W  = (colBase < DIMK) ? Wh : Wt;
  const float* bb = (colBase < DIMK) ? bh : bt;
  float* Out            = (colBase < DIMK) ? Eh : Et;
  unsigned short* Outb  = (colBase < DIMK) ? Ehb : Etb;
  const int colOff = colBase & (DIMK - 1);

  const int tx = tid & 15, ty = tid >> 4;
  f32x2 acc2[8][4];
#pragma unroll
  for (int r = 0; r < 8; ++r)
#pragma unroll
    for (int p = 0; p < 4; ++p) acc2[r][p] = (f32x2){0.f, 0.f};

  auto stage = [&](int buf, int kt) {
#pragma unroll
    for (int u = 0; u < 2; ++u) {      // A tile: 512 float4 (4 per 16-k row)
      const int idx = tid + u * NTHREADS;
      const int r = idx >> 2;          // 0..127
      const int dc = idx & 3;          // k-quad within 16
      const float4 av = *(const float4*)&X[(size_t)(rowBase + r) * DIMK + kt + dc * 4];
      As[buf][dc * 4 + 0][r] = av.x; As[buf][dc * 4 + 1][r] = av.y;
      As[buf][dc * 4 + 2][r] = av.z; As[buf][dc * 4 + 3][r] = av.w;
    }
#pragma unroll
    for (int u = 0; u < 2; ++u) {      // B tile: 512 float4
      const int idx = tid + u * NTHREADS;
      const int r = idx >> 2;
      const int dc = idx & 3;
      const float4 bv = *(const float4*)&W[(size_t)(colOff + r) * DIMK + kt + dc * 4];
      Bs[buf][dc * 4 + 0][r] = bv.x; Bs[buf][dc * 4 + 1][r] = bv.y;
      Bs[buf][dc * 4 + 2][r] = bv.z; Bs[buf][dc * 4 + 3][r] = bv.w;
    }
  };
  auto compute = [&](int buf) {
#pragma unroll 4
    for (int k = 0; k < ETK; ++k) {
      const float4 a0 = *(const float4*)&As[buf][k][ty * 4];
      const float4 a1 = *(const float4*)&As[buf][k][64 + ty * 4];
      const float4 b0 = *(const float4*)&Bs[buf][k][tx * 4];
      const float4 b1 = *(const float4*)&Bs[buf][k][64 + tx * 4];
      const float ar[8] = {a0.x, a0.y, a0.z, a0.w, a1.x, a1.y, a1.z, a1.w};
      const f32x2 bp[4] = {(f32x2){b0.x, b0.y}, (f32x2){b0.z, b0.w},
                           (f32x2){b1.x, b1.y}, (f32x2){b1.z, b1.w}};
#pragma unroll
      for (int r = 0; r < 8; ++r) {
        const f32x2 ar2 = (f32x2){ar[r], ar[r]};
#pragma unroll
        for (int p = 0; p < 4; ++p)
          acc2[r][p] = pk_fma(ar2, bp[p], acc2[r][p]);
      }
    }
  };

  stage(0, 0);
  __syncthreads();
#pragma unroll 1
  for (int ki = 0; ki < DIMK / ETK; ki += 2) {
    if (ki + 1 < DIMK / ETK) stage(1, (ki + 1) * ETK);
    compute(0);                  // k ascending -> chain bit-identical
    __syncthreads();
    if (ki + 2 < DIMK / ETK) stage(0, (ki + 2) * ETK);
    compute(1);
    __syncthreads();
  }

  float br[8];
  {
    const float4 bv0 = *(const float4*)&bb[colOff + tx * 4];
    const float4 bv1 = *(const float4*)&bb[colOff + 64 + tx * 4];
    br[0] = bv0.x; br[1] = bv0.y; br[2] = bv0.z; br[3] = bv0.w;
    br[4] = bv1.x; br[5] = bv1.y; br[6] = bv1.z; br[7] = bv1.w;
  }
#pragma unroll
  for (int r = 0; r < 8; ++r) {
    const int row = rowBase + ((r < 4) ? (ty * 4 + r) : (64 + ty * 4 + r - 4));
    float4 o0, o1;
    o0.x = acc2[r][0][0] + br[0]; o0.y = acc2[r][0][1] + br[1];
    o0.z = acc2[r][1][0] + br[2]; o0.w = acc2[r][1][1] + br[3];
    o1.x = acc2[r][2][0] + br[4]; o1.y = acc2[r][2][1] + br[5];
    o1.z = acc2[r][3][0] + br[6]; o1.w = acc2[r][3][1] + br[7];
    const size_t off0 = (size_t)row * DIMK + colOff + tx * 4;
    const size_t off1 = off0 + 64;
    *(float4*)&Out[off0] = o0;
    *(float4*)&Out[off1] = o1;
    ushort4 q0, q1;
    q0.x = f2bf(o0.x); q0.y = f2bf(o0.y); q0.z = f2bf(o0.z); q0.w = f2bf(o0.w);
    q1.x = f2bf(o1.x); q1.y = f2bf(o1.y); q1.z = f2bf(o1.z); q1.w = f2bf(o1.w);
    *(ushort4*)&Outb[off0] = q0;
    *(ushort4*)&Outb[off1] = q1;
  }
}

// ---------------------------------------------------------------------------
// Screen (r31 exact, part of the 340.6-us best build): phase-split +
// counted vmcnt + swizzle, default block order. The one measured screen
// win (-15 us vs the 2-barrier structure); all other levers null/negative
// (r22 stores, r23/r33 XCD remaps, r24 coarse ring, r25 chunk-major,
// r26 occupancy). Closed out.
// ---------------------------------------------------------------------------
__global__ __launch_bounds__(SNT, 4)
void screen_store(const unsigned short* __restrict__ Ehb,
                  const unsigned short* __restrict__ Etb,
                  float* __restrict__ tmax, unsigned short* __restrict__ Sc) {
  __shared__ __align__(16) unsigned short pool[3 * (ASZ + BSZ)];   // 73728 B
  unsigned short* const Abase = pool;                 // 3 x 4096 ushorts
  unsigned short* const Bbase = pool + 3 * ASZ;       // 3 x 8192 ushorts
  unsigned short* const Csb = pool;   // epilogue alias: 128 x 72 = 18.4 KB

  const int tid = threadIdx.x;
  const int rowBase = blockIdx.x * BM;
  const int strip = blockIdx.y;

  const int w = tid >> 6, lane = tid & 63;
  const int q = lane >> 4, l15 = lane & 15;
  const int wr = (w & 1) * 64, wc = (w >> 1) * 64;   // 2x4 wave grid, 64x64 tiles
  const int rr = tid >> 2, sub = tid & 3;            // epilogue: row / 16B chunk pair

  const int wb0 = __builtin_amdgcn_readfirstlane(tid & ~63);
  const int ar0 = tid >> 2;
  // swizzled source chunk: chunk ^ ((row>>1)&3); row = tid>>2 so the
  // XOR key is (tid>>3)&3 (identical for the B slot tid+512). 4-lane
  // groups read a permutation of the same 64B line -> coalescing intact.
  const int acS = (((tid & 3) ^ ((tid >> 3) & 3))) * 8;

  // precomputed swizzled ds_read addrs (ushort units), fixed per thread
  int aAddr[4], bAddr[4];
#pragma unroll
  for (int i = 0; i < 4; ++i) {
    const int row = wr + i * 16 + l15;
    aAddr[i] = (row * 4 + (q ^ ((row >> 1) & 3))) * 8;
  }
#pragma unroll
  for (int j = 0; j < 4; ++j) {
    const int col = wc + j * 16 + l15;
    bAddr[j] = (col * 4 + (q ^ ((col >> 1) & 3))) * 8;
  }

  for (int ct = 0; ct < SCOLS2; ct += BN) {
    const int colBase = strip * SCOLS2 + ct;
    f32x4 acc[4][4];
#pragma unroll
    for (int i = 0; i < 4; ++i)
#pragma unroll
      for (int j = 0; j < 4; ++j) acc[i][j] = (f32x4){0.f, 0.f, 0.f, 0.f};

    auto stageS = [&](int bsel, int kt) {
      unsigned short* Ad = Abase + bsel * ASZ;
      unsigned short* Bd = Bbase + bsel * BSZ;
      gld16(Ehb + (size_t)(rowBase + ar0) * DIMK + kt + acS, Ad + wb0 * 8);
      gld16(Etb + (size_t)(colBase + ar0) * DIMK + kt + acS, Bd + wb0 * 8);
      gld16(Etb + (size_t)(colBase + 128 + ar0) * DIMK + kt + acS,
            Bd + (wb0 + 512) * 8);
    };

    // ring prologue: tiles 0,1 staged (6 outstanding); wait for tile 0
    stageS(0, 0);
    stageS(1, BK);
    asm volatile("s_waitcnt vmcnt(3)" ::: "memory");
    __builtin_amdgcn_s_barrier();
    asm volatile("" ::: "memory");

    int oc = 0, on = 1, op = 2;
#pragma unroll 1
    for (int t = 0; t < NT; ++t) {
      const unsigned short* Ac = Abase + oc * ASZ;
      const unsigned short* Bc = Bbase + oc * BSZ;
      bf16x8 af[4], bfr[4];
      // ---- phase 1: af[0..3] + bf[0..1], issue t+2 stage, MFMA j=0,1 ----
#pragma unroll
      for (int i = 0; i < 4; ++i) af[i] = *(const bf16x8*)&Ac[aAddr[i]];
#pragma unroll
      for (int j = 0; j < 2; ++j) bfr[j] = *(const bf16x8*)&Bc[bAddr[j]];
      if (t + 2 < NT) stageS(op, (t + 2) * BK);
      __builtin_amdgcn_s_setprio(1);
#pragma unroll
      for (int i = 0; i < 4; ++i)
#pragma unroll
        for (int j = 0; j < 2; ++j)
          acc[i][j] = __builtin_amdgcn_mfma_f32_16x16x32_bf16(af[i], bfr[j], acc[i][j], 0, 0, 0);
      __builtin_amdgcn_s_setprio(0);
      __builtin_amdgcn_s_barrier();      // mid-tile role-split barrier
      asm volatile("" ::: "memory");
      // ---- phase 2: bf[2..3], MFMA j=2,3 ----
#pragma unroll
      for (int j = 2; j < 4; ++j) bfr[j] = *(const bf16x8*)&Bc[bAddr[j]];
      __builtin_amdgcn_s_setprio(1);
#pragma unroll
      for (int i = 0; i < 4; ++i)
#pragma unroll
        for (int j = 2; j < 4; ++j)
          acc[i][j] = __builtin_amdgcn_mfma_f32_16x16x32_bf16(af[i], bfr[j], acc[i][j], 0, 0, 0);
      __builtin_amdgcn_s_setprio(0);
      if (t + 1 < NT) {
        // tile t+1's loads (issued at t-1) must be complete; t+2's 3 may fly
        if (t + 2 < NT) asm volatile("s_waitcnt vmcnt(3)" ::: "memory");
        else            asm volatile("s_waitcnt vmcnt(0)" ::: "memory");
        __builtin_amdgcn_s_barrier();
        asm volatile("" ::: "memory");
      }
      const int tmp = oc; oc = on; on = op; op = tmp;
    }
    __syncthreads();   // full drain: staging pool dead -> Csb alias valid.

#pragma unroll
    for (int qtr = 0; qtr < 4; ++qtr) {
      // dump: the 2 waves (row halves) owning this 64-col quarter
      if ((w >> 1) == qtr) {
#pragma unroll
        for (int i = 0; i < 4; ++i)
#pragma unroll
          for (int j = 0; j < 4; ++j)
#pragma unroll
            for (int rg = 0; rg < 4; ++rg)
              Csb[(wr + i * 16 + q * 4 + rg) * 72 + j * 16 + l15] =
                  f2bf(acc[i][j][rg]);
      }
      __syncthreads();
      // readback: 4 threads/row, 16 cols (2 uint4) each
      float m = -INFINITY;
      uint4 buf4[2];
#pragma unroll
      for (int k = 0; k < 2; ++k) {
        buf4[k] = *(const uint4*)&Csb[rr * 72 + sub * 16 + k * 8];
        const unsigned int uu[4] = {buf4[k].x, buf4[k].y, buf4[k].z, buf4[k].w};
#pragma unroll
        for (int e = 0; e < 4; ++e) {
          m = fmaxf(m, __uint_as_float(uu[e] << 16));
          m = fmaxf(m, __uint_as_float(uu[e] & 0xFFFF0000u));
        }
      }
      m = fmaxf(m, __shfl_xor(m, 1, 64));   // pair subs {0,1} / {2,3}: 32-col max
      const int gbase = (colBase + qtr * 64) >> 5;   // global 32-col group
      if ((sub & 1) == 0)
        tmax[(size_t)(rowBase + rr) * NQ + gbase + (sub >> 1)] = m;
      uint4* dst = (uint4*)&Sc[(size_t)(rowBase + rr) * NROWS + colBase + qtr * 64 + sub * 16];
      dst[0] = buf4[0];
      dst[1] = buf4[1];
      __syncthreads();   // readback done before next dump / next ct staging
    }
  }
}

// ---------------------------------------------------------------------------
// Merged tail (r8 exact, best measured): block-per-row chunk-skip collect +
// wave-0 rescore. r9/r10 restructures were null -> collect is bound by
// structure-invariant diverged-gather traffic; serial ascending-fmaf chain
// is load-bearing (r27). Keep verbatim.
// ---------------------------------------------------------------------------
__global__ __launch_bounds__(256)
void collect_rescore(const unsigned short* __restrict__ Sc,
                     const float* __restrict__ tmax,
                     const float* __restrict__ Eh, const float* __restrict__ Et,
                     float* __restrict__ out) {
  __shared__ float tm[NQ];     // 1 KB: the row's 256 group maxes
  __shared__ float tts;
  __shared__ int lcnt;
  __shared__ int lcand[CAP];
  const int tid = threadIdx.x;
  const int lane = tid & 63;
  const int wid = tid >> 6;
  const int r = blockIdx.x;

  if (tid == 0) lcnt = 0;
  tm[tid] = tmax[(size_t)r * NQ + tid];   // coalesced 1 KB row load
  __syncthreads();

  // --- threshold (wave 0): identical knockout semantics ---
  if (wid == 0) {
    float a0 = tm[lane * 4 + 0], a1 = tm[lane * 4 + 1];
    float a2 = tm[lane * 4 + 2], a3 = tm[lane * 4 + 3];
    float g = -INFINITY;
#pragma unroll 1
    for (int j = 0; j < TOPK; ++j) {
      const float lm = fmaxf(fmaxf(a0, a1), fmaxf(a2, a3));
      g = lm;
#pragma unroll
      for (int off = 32; off > 0; off >>= 1) g = fmaxf(g, __shfl_xor(g, off, 64));
      const unsigned long long ball = __ballot(lm == g);
      const int src = __ffsll((long long)ball) - 1;
      if (lane == src) {
        if      (a0 == g) a0 = -INFINITY;
        else if (a1 == g) a1 = -INFINITY;
        else if (a2 == g) a2 = -INFINITY;
        else              a3 = -INFINITY;
      }
    }
    if (lane == 0) tts = g - TMARGIN;
  }
  __syncthreads();
  const float tt = tts;

  // --- chunk-skip scan: thread t handles 32-col group t ---
  if (tm[tid] >= tt) {
    const unsigned short* chunk = Sc + (size_t)r * NROWS + tid * 32;
#pragma unroll
    for (int k = 0; k < 4; ++k) {
      const uint4 u = *(const uint4*)&chunk[k * 8];
      const unsigned int uu[4] = {u.x, u.y, u.z, u.w};
#pragma unroll
      for (int e = 0; e < 4; ++e) {
        const float lo = __uint_as_float(uu[e] << 16);
        const float hi = __uint_as_float(uu[e] & 0xFFFF0000u);
        const int c0 = tid * 32 + k * 8 + 2 * e;
        if (lo >= tt) {
          const int p = atomicAdd(&lcnt, 1);
          if (p < CAP) lcand[p] = c0;
        }
        if (hi >= tt) {
          const int p = atomicAdd(&lcnt, 1);
          if (p < CAP) lcand[p] = c0 + 1;
        }
      }
    }
  }
  __syncthreads();   // candidate list complete
  if (wid != 0) return;

  // --- rescore on wave 0: chain BIT-IDENTICAL (serial ascending fmaf) ---
  const int n = min(lcnt, CAP);
  const bool active = lane < n;
  const int col = active ? lcand[lane] : 0;

  const float* a = Eh + (size_t)r * DIMK;
  const float* b = Et + (size_t)col * DIMK;
  float p = 0.f;
#pragma unroll 4
  for (int k = 0; k < DIMK; k += 4) {
    const float4 av = *(const float4*)&a[k];
    const float4 bv = *(const float4*)&b[k];
    p = fmaf(av.x, bv.x, p);
    p = fmaf(av.y, bv.y, p);
    p = fmaf(av.z, bv.z, p);
    p = fmaf(av.w, bv.w, p);
  }
  float v = active ? p * SCALE : -INFINITY;
  const int vc = active ? col : 0x7FFFFFFF;

  // 10 rounds of wave-max (tie -> min col); lane j keeps round-j winner.
  float myv = -INFINITY; int myc = 0; float m = 0.f;
  float vv = v; int cc2 = vc;
#pragma unroll 1
  for (int j = 0; j < TOPK; ++j) {
    float bvv = vv; int bcc = cc2;
#pragma unroll
    for (int off = 32; off > 0; off >>= 1) {
      const float ov = __shfl_xor(bvv, off, 64);
      const int oc = __shfl_xor(bcc, off, 64);
      if (ov > bvv || (ov == bvv && oc < bcc)) { bvv = ov; bcc = oc; }
    }
    if (j == 0) m = bvv;
    if (lane == j) { myv = bvv; myc = bcc; }
    if (vv == bvv && cc2 == bcc) vv = -INFINITY;   // knock out (cols unique)
  }

  // softmax: gather the 10 values, sum sequentially (rank order, as before).
  float sum = 0.f;
#pragma unroll
  for (int j = 0; j < TOPK; ++j) sum += expf(__shfl(myv, j, 64) - m);
  const float inv = 1.0f / sum;

  if (lane < TOPK) {
    const size_t ro = (size_t)r * TOPK + lane;
    out[ro] = (float)r;                                   // src
    out[(size_t)NROWS * TOPK + ro] = (float)myc;          // dst
    out[2 * (size_t)NROWS * TOPK + ro] = expf(myv - m) * inv;  // weight
  }
}

// ---------------------------------------------------------------------------
extern "C" void kernel_launch(void* const* d_in, const int* in_sizes, int n_in,
                              void* d_out, int out_size, void* d_ws, size_t ws_size,
                              hipStream_t stream) {
  const float* X  = (const float*)d_in[0];
  const float* Wh = (const float*)d_in[1];
  const float* bh = (const float*)d_in[2];
  const float* Wt = (const float*)d_in[3];
  const float* bt = (const float*)d_in[4];
  float* out = (float*)d_out;

  char* ws = (char*)d_ws;
  const size_t embB  = (size_t)NROWS * DIMK * sizeof(float);          // 16 MB
  const size_t embBH = (size_t)NROWS * DIMK * sizeof(unsigned short); //  8 MB
  const size_t tmaxB = (size_t)NROWS * NQ * sizeof(float);            //  8 MB
  float* Eh   = (float*)ws;
  float* Et   = (float*)(ws + embB);
  unsigned short* Ehb = (unsigned short*)(ws + 2 * embB);
  unsigned short* Etb = (unsigned short*)(ws + 2 * embB + embBH);
  float* tmax = (float*)(ws + 2 * embB + 2 * embBH);
  unsigned short* Sc = (unsigned short*)(ws + 2 * embB + 2 * embBH + tmaxB);
  // total ws use ~176 MB

  dim3 blk(NTHREADS);
  dim3 g1(NROWS / ETM, (2 * DIMK) / ETN);      // 64 x 8
  embed_gemm<<<g1, blk, 0, stream>>>(X, Wh, bh, Wt, bt, Eh, Et, Ehb, Etb);

  dim3 blkS(SNT);
  dim3 g2(NROWS / BM, NS2);                    // 64 x 16 (1024 blocks)
  screen_store<<<g2, blkS, 0, stream>>>(Ehb, Etb, tmax, Sc);

  collect_rescore<<<NROWS, blk, 0, stream>>>(Sc, tmax, Eh, Et, out);
}